// Round 12
// baseline (276.800 us; speedup 1.0000x reference)
//
#include <hip/hip_runtime.h>
#include <hip/hip_bf16.h>

#define B_    2
#define H_    512
#define W_    512
#define HW_   262144   // 512*512
#define EPSV  1e-12f

typedef __hip_bfloat16 bf16;
typedef __fp16 h16x8 __attribute__((ext_vector_type(8)));
typedef float f32x4 __attribute__((ext_vector_type(4)));

// ---------------------------------------------------------------------------
// K1a: 1x1 conv as f16 MFMA GEMM, 4 tiles/block, software-pipelined.
// LDS-bounce epilogue in TWO o-half passes -> Bo halved -> LDS 49 KB ->
// 3 blocks/CU (was 2). Latency-bound kernel: +50% resident waves.
__global__ __launch_bounds__(256) void k1a_conv1x1(
    const float* __restrict__ x, const float* __restrict__ kv_w,
    const float* __restrict__ kv_b, bf16* __restrict__ kv1) {
  const int tid = threadIdx.x;
  const int base = blockIdx.x * 512;   // 4 tiles of 128 px, same b
  const int b  = base >> 18;
  const int sb = base & (HW_ - 1);
  __shared__ __fp16 Wl[8 * 128 * 8];   // [kg][o][e]    16 KB
  __shared__ __fp16 Xe[8 * 64 * 8];    // [kg][px/2][e]  8 KB (even px)
  __shared__ __fp16 Xo[8 * 64 * 8];    // [kg][px/2][e]  8 KB (odd px)
  __shared__ bf16 Bo[64 * 136];        // half-bounce [o64][px], 17 KB

  // ---- stage W once: thread t -> o = t>>1, k-half = t&1 (32 k's) ----
  {
    const int o = tid >> 1, half = tid & 1;
    const float* wp = kv_w + o * 64 + half * 32;
#pragma unroll
    for (int j = 0; j < 4; ++j) {
      const float4 a = *reinterpret_cast<const float4*>(wp + j * 8);
      const float4 c = *reinterpret_cast<const float4*>(wp + j * 8 + 4);
      h16x8 h;
      h[0] = (__fp16)a.x; h[1] = (__fp16)a.y; h[2] = (__fp16)a.z; h[3] = (__fp16)a.w;
      h[4] = (__fp16)c.x; h[5] = (__fp16)c.y; h[6] = (__fp16)c.z; h[7] = (__fp16)c.w;
      *reinterpret_cast<h16x8*>(&Wl[((half * 4 + j) * 128 + o) * 8]) = h;
    }
  }
  // ---- x staging geometry: thread -> px pair (2m,2m+1), 16 planes ----
  const int m = tid & 63, kgq = tid >> 6;
  const float* xbase = x + (size_t)b * 64 * HW_ + sb + m * 2;

  float2 cur[16], nxt[16];
#pragma unroll
  for (int u = 0; u < 16; ++u)
    cur[u] = *reinterpret_cast<const float2*>(xbase + (size_t)(kgq * 16 + u) * HW_);

  const int wv = tid >> 6, lane = tid & 63;
  const int m0 = (wv & 1) * 64, n0 = (wv >> 1) * 64;
  const int lr = lane & 15, lg = lane >> 4;
  const int oo = tid >> 4;          // 0..15 (store row group)
  const int pxc = (tid & 15) * 8;   // 0..120 (store col chunk)

#pragma unroll
  for (int t = 0; t < 4; ++t) {
    // ---- pack cur -> LDS (single buffer; WAR-safe: X dead after MFMA) ----
#pragma unroll
    for (int kk = 0; kk < 2; ++kk) {
      h16x8 he, ho;
#pragma unroll
      for (int e = 0; e < 8; ++e) {
        he[e] = (__fp16)cur[kk * 8 + e].x;
        ho[e] = (__fp16)cur[kk * 8 + e].y;
      }
      const int kg = kgq * 2 + kk;
      *reinterpret_cast<h16x8*>(&Xe[(kg * 64 + m) * 8]) = he;
      *reinterpret_cast<h16x8*>(&Xo[(kg * 64 + m) * 8]) = ho;
    }
    __syncthreads();   // barA: pack visible
    // ---- prefetch next tile's x (issues overlap MFMA + epilogue) ----
    if (t < 3) {
#pragma unroll
      for (int u = 0; u < 16; ++u)
        nxt[u] = *reinterpret_cast<const float2*>(
            xbase + (t + 1) * 128 + (size_t)(kgq * 16 + u) * HW_);
    }
    // ---- MFMA: wave covers M-half (wv&1)*64, N-half (wv>>1)*64 ----
    const __fp16* xb2 = (lr & 1) ? Xo : Xe;
    f32x4 acc[4][4];
#pragma unroll
    for (int mt = 0; mt < 4; ++mt)
#pragma unroll
      for (int nt = 0; nt < 4; ++nt) acc[mt][nt] = (f32x4){0.f, 0.f, 0.f, 0.f};
#pragma unroll
    for (int ks = 0; ks < 2; ++ks) {
      h16x8 af[4], bfr[4];
#pragma unroll
      for (int mt = 0; mt < 4; ++mt)
        af[mt] = *reinterpret_cast<const h16x8*>(
            &Wl[((ks * 4 + lg) * 128 + m0 + mt * 16 + lr) * 8]);
#pragma unroll
      for (int nt = 0; nt < 4; ++nt)
        bfr[nt] = *reinterpret_cast<const h16x8*>(
            &xb2[((ks * 4 + lg) * 64 + (n0 >> 1) + nt * 8 + (lr >> 1)) * 8]);
#pragma unroll
      for (int mt = 0; mt < 4; ++mt)
#pragma unroll
        for (int nt = 0; nt < 4; ++nt)
          acc[mt][nt] = __builtin_amdgcn_mfma_f32_16x16x32_f16(
              af[mt], bfr[nt], acc[mt][nt], 0, 0, 0);
    }
    // ---- epilogue: two o-half passes through the half-size bounce ----
    bf16* dstt = kv1 + (size_t)b * 128 * HW_ + sb + t * 128 + pxc;
#pragma unroll
    for (int hh = 0; hh < 2; ++hh) {
      if ((wv & 1) == hh) {   // waves owning this o-half bounce their acc
#pragma unroll
        for (int mt = 0; mt < 4; ++mt) {
#pragma unroll
          for (int r = 0; r < 4; ++r) {
            const int o = mt * 16 + lg * 4 + r;        // 0..63 within half
            const float bv = kv_b[hh * 64 + o];
#pragma unroll
            for (int nt = 0; nt < 4; ++nt)
              Bo[o * 136 + n0 + nt * 16 + lr] =
                  __float2bfloat16(acc[mt][nt][r] + bv);
          }
        }
      }
      __syncthreads();   // bounce visible (also protects Bo reuse / X)
      // all threads store this o-half: 4 full 256B o-rows per inst
#pragma unroll
      for (int rr = 0; rr < 4; ++rr) {
        const int o = oo + rr * 16;                    // 0..63 within half
        const int4 v = *reinterpret_cast<const int4*>(&Bo[o * 136 + pxc]);
        *reinterpret_cast<int4*>(dstt + (size_t)(hh * 64 + o) * HW_) = v;
      }
      __syncthreads();   // store reads done before Bo rewrite / next pack
    }
    // ---- rotate prefetch registers ----
    if (t < 3) {
#pragma unroll
      for (int u = 0; u < 16; ++u) cur[u] = nxt[u];
    }
  }
}

// ---------------------------------------------------------------------------
// K1b: depthwise 3x3 (pad=1) on bf16 kv1 -> bf16 k||v (in d_out), fp32 math.
// Halo cols via wave shuffle.
__global__ __launch_bounds__(256) void k1b_dw(
    const bf16* __restrict__ kv1, const float* __restrict__ dw_w,
    const float* __restrict__ dw_b, bf16* __restrict__ kvout,
    float* __restrict__ ssqpart) {
  const int tid = threadIdx.x;
  const int cchunk = tid & 63;            // 64 col-chunks of 8
  const int ch_sub = tid >> 6;            // 4 channels per block
  const int rs = blockIdx.x;              // 16 row strips of 32
  const int chgrp = blockIdx.y;           // 32
  const int b = blockIdx.z;
  const int ch = chgrp * 4 + ch_sub;
  const int c0 = cchunk * 8;
  const int r0 = rs * 32;
  const bf16* src = kv1 + (size_t)(b * 128 + ch) * HW_;
  const bool is_k = (ch < 64);
  const size_t obase = is_k ? (size_t)(b * 64 + ch) * HW_
                            : (size_t)(128 + b * 64 + (ch - 64)) * HW_;
  bf16* dst = kvout + obase;
  float dwr[9];
#pragma unroll
  for (int t = 0; t < 9; ++t) dwr[t] = dw_w[ch * 9 + t];
  const float bd = dw_b[ch];

  float a0[10], a1[10], a2[10];
  auto loadrow = [&](int gr, float* a) {
    if (gr < 0 || gr >= H_) {
#pragma unroll
      for (int t = 0; t < 10; ++t) a[t] = 0.f;
      return;
    }
    union { int4 v; bf16 h[8]; } raw;
    raw.v = *reinterpret_cast<const int4*>(src + (size_t)gr * W_ + c0);
#pragma unroll
    for (int t = 0; t < 8; ++t) a[t + 1] = __bfloat162float(raw.h[t]);
    const float left = __shfl_up(a[8], 1);     // lane-1's col c0-1
    const float right = __shfl_down(a[1], 1);  // lane+1's col c0+8
    a[0] = (cchunk == 0) ? 0.f : left;
    a[9] = (cchunk == 63) ? 0.f : right;
  };
  loadrow(r0 - 1, a0);
  loadrow(r0, a1);
  float sq = 0.f;
#pragma unroll 4
  for (int rr = 0; rr < 32; ++rr) {
    loadrow(r0 + rr + 1, a2);
    union { int4 v; bf16 h[8]; } ou;
#pragma unroll
    for (int j = 0; j < 8; ++j) {
      const float ov = bd
          + dwr[0] * a0[j] + dwr[1] * a0[j + 1] + dwr[2] * a0[j + 2]
          + dwr[3] * a1[j] + dwr[4] * a1[j + 1] + dwr[5] * a1[j + 2]
          + dwr[6] * a2[j] + dwr[7] * a2[j + 1] + dwr[8] * a2[j + 2];
      sq += ov * ov;
      ou.h[j] = __float2bfloat16(ov);
    }
    *reinterpret_cast<int4*>(dst + (size_t)(r0 + rr) * W_ + c0) = ou.v;
#pragma unroll
    for (int t = 0; t < 10; ++t) { a0[t] = a1[t]; a1[t] = a2[t]; }
  }
  // wave reduction of sq over the 64 col-chunk lanes (same ch per wave)
#pragma unroll
  for (int off = 32; off > 0; off >>= 1) sq += __shfl_down(sq, off, 64);
  if (is_k && cchunk == 0)
    ssqpart[(size_t)(b * 64 + ch) * 16 + rs] = sq;
}

// ---------------------------------------------------------------------------
// K2: reduce sumsq partials -> rnorm; qn = sign(q)*rnorm*temps (k0 folded in)
__global__ __launch_bounds__(256) void k2_finalize(
    const float* __restrict__ ssqpart, const float* __restrict__ temps,
    const float* __restrict__ metainfo, const float* __restrict__ Wq,
    const float* __restrict__ bq, float* __restrict__ rnorm,
    float* __restrict__ qn) {
  const int tid = threadIdx.x;
  if (tid < 128) {
    const int b = tid >> 6, c = tid & 63;
    float s = 0.f;
    for (int p = 0; p < 16; ++p) s += ssqpart[(size_t)(b * 64 + c) * 16 + p];
    rnorm[tid] = 1.f / fmaxf(sqrtf(s), EPSV);
  }
  __syncthreads();
  for (int idx = tid; idx < 512; idx += 256) {
    const int b = idx >> 8, n = (idx >> 6) & 3, d = idx & 63;
    float acc = bq[n * 64 + d];
#pragma unroll
    for (int m = 0; m < 4; ++m)
      acc += metainfo[(b * 4 + n) * 4 + m] * Wq[(n * 64 + d) * 4 + m];
    const float sgn = acc / fmaxf(fabsf(acc), EPSV);
    qn[idx] = sgn * rnorm[b * 64 + d] * temps[n * 8 + (d >> 3)];
  }
}

// ---------------------------------------------------------------------------
// K3: softmax denominators from bf16 k. 8 px/thread, 16B k loads.
__global__ __launch_bounds__(256) void k3_denom(
    const bf16* __restrict__ kbuf, const float* __restrict__ qn,
    float* __restrict__ dpart) {
  const int tile = blockIdx.x, e = blockIdx.y, b = blockIdx.z;
  const int tid = threadIdx.x;
  float q[4][8];
#pragma unroll
  for (int n = 0; n < 4; ++n)
#pragma unroll
    for (int cc = 0; cc < 8; ++cc)
      q[n][cc] = qn[b * 256 + n * 64 + e * 8 + cc];
  const bf16* kb = kbuf + (size_t)(b * 64 + e * 8) * HW_;
  float dsum[4] = {0.f, 0.f, 0.f, 0.f};
  const int sbase = tile * 4096;
#pragma unroll
  for (int it = 0; it < 2; ++it) {
    const int s = sbase + (it * 256 + tid) * 8;
    float kf[8][8];
#pragma unroll
    for (int cc = 0; cc < 8; ++cc) {
      union { int4 v; bf16 h[8]; } r;
      r.v = *reinterpret_cast<const int4*>(kb + (size_t)cc * HW_ + s);
#pragma unroll
      for (int j = 0; j < 8; ++j) kf[cc][j] = __bfloat162float(r.h[j]);
    }
#pragma unroll
    for (int n = 0; n < 4; ++n) {
#pragma unroll
      for (int px = 0; px < 8; ++px) {
        float l = 0.f;
#pragma unroll
        for (int cc = 0; cc < 8; ++cc) l += q[n][cc] * kf[cc][px];
        dsum[n] += __expf(l);
      }
    }
  }
  __shared__ float red[256];
#pragma unroll
  for (int n = 0; n < 4; ++n) {
    red[tid] = dsum[n];
    __syncthreads();
    for (int st = 128; st > 0; st >>= 1) {
      if (tid < st) red[tid] += red[tid + st];
      __syncthreads();
    }
    if (tid == 0) dpart[(b * 32 + n * 8 + e) * 64 + tile] = red[0];
    __syncthreads();
  }
}

// ---------------------------------------------------------------------------
// K4: mid[b,cc,s] = sum_e (sum_n exp(l)/denom) * v[b,e,cc,s]  (bf16 k,v)
__global__ __launch_bounds__(256) void k4_attend(
    const bf16* __restrict__ kvbuf, const float* __restrict__ qn,
    const float* __restrict__ dpart, float* __restrict__ mid) {
  const int b = blockIdx.y;
  const int tid = threadIdx.x;
  __shared__ float qnl[256];
  __shared__ float rdl[32];
  qnl[tid] = qn[b * 256 + tid];
  if (tid < 32) {
    float s = 0.f;
    for (int t = 0; t < 64; ++t) s += dpart[(b * 32 + tid) * 64 + t];
    rdl[tid] = 1.f / s;
  }
  __syncthreads();
  const bf16* kb = kvbuf + (size_t)(b * 64) * HW_;
  const bf16* vb = kvbuf + (size_t)(128 + b * 64) * HW_;
  float* mb = mid + (size_t)b * 8 * HW_;
  const int s = (blockIdx.x * 256 + tid) * 4;
  float macc[8][4];
#pragma unroll
  for (int cc = 0; cc < 8; ++cc)
#pragma unroll
    for (int px = 0; px < 4; ++px) macc[cc][px] = 0.f;
#pragma unroll
  for (int e = 0; e < 8; ++e) {
    float kf[8][4];
#pragma unroll
    for (int cc = 0; cc < 8; ++cc) {
      union { ushort4 v; bf16 h[4]; } r;
      r.v = *reinterpret_cast<const ushort4*>(kb + (size_t)(e * 8 + cc) * HW_ + s);
#pragma unroll
      for (int px = 0; px < 4; ++px) kf[cc][px] = __bfloat162float(r.h[px]);
    }
    float wsum[4] = {0.f, 0.f, 0.f, 0.f};
#pragma unroll
    for (int n = 0; n < 4; ++n) {
      const float rd = rdl[n * 8 + e];
#pragma unroll
      for (int px = 0; px < 4; ++px) {
        float l = 0.f;
#pragma unroll
        for (int cc = 0; cc < 8; ++cc) l += qnl[n * 64 + e * 8 + cc] * kf[cc][px];
        wsum[px] += __expf(l) * rd;
      }
    }
#pragma unroll
    for (int cc = 0; cc < 8; ++cc) {
      union { ushort4 v; bf16 h[4]; } r;
      r.v = *reinterpret_cast<const ushort4*>(vb + (size_t)(e * 8 + cc) * HW_ + s);
#pragma unroll
      for (int px = 0; px < 4; ++px)
        macc[cc][px] += wsum[px] * __bfloat162float(r.h[px]);
    }
  }
#pragma unroll
  for (int cc = 0; cc < 8; ++cc)
    *reinterpret_cast<float4*>(mb + (size_t)cc * HW_ + s) =
        make_float4(macc[cc][0], macc[cc][1], macc[cc][2], macc[cc][3]);
}

// ---------------------------------------------------------------------------
// K5: grouped 3x3 (8->64, groups=8) + exact GELU + 1x1 (64->64) via f16 MFMA.
__global__ __launch_bounds__(256) void k5_cross(
    const float* __restrict__ mid, const float* __restrict__ cc1_w,
    const float* __restrict__ cc1_b, const float* __restrict__ cc2_w,
    const float* __restrict__ cc2_b, float* __restrict__ out) {
  const int tid = threadIdx.x;
  const int c0 = blockIdx.x * 128;
  const int r0 = blockIdx.y * 2;
  const int b = blockIdx.z;
  __shared__ float midl[8 * 4 * 132];   // [ch][4 rows][132]  16.5 KB
  __shared__ __fp16 gs[256 * 64];       // [px][oo] swizzled  32 KB
  __shared__ __fp16 w2s[64 * 64];       // [p][oo] swizzled    8 KB
  __shared__ float w1l[576];
  __shared__ float b1l[64], b2l[64];
  // stage mid tile (coalesced along cols)
  for (int idx = tid; idx < 8 * 4 * 130; idx += 256) {
    const int ch = idx / 520;
    const int rem = idx % 520;
    const int dr = rem / 130, lc = rem % 130;
    const int gr = r0 - 1 + dr, gc = c0 - 1 + lc;
    float v = 0.f;
    if (gr >= 0 && gr < H_ && gc >= 0 && gc < W_)
      v = mid[(size_t)(b * 8 + ch) * HW_ + (size_t)gr * W_ + gc];
    midl[(ch * 4 + dr) * 132 + lc] = v;
  }
  // stage w2 as f16 chunks: w2s[p][ooc^(p&7)] = cc2_w[p][ooc*8..+8]
#pragma unroll
  for (int rr = 0; rr < 2; ++rr) {
    const int idx = tid + rr * 256;
    const int p = idx >> 3, ooc = idx & 7;
    const float4 a = *reinterpret_cast<const float4*>(cc2_w + p * 64 + ooc * 8);
    const float4 c = *reinterpret_cast<const float4*>(cc2_w + p * 64 + ooc * 8 + 4);
    h16x8 h;
    h[0] = (__fp16)a.x; h[1] = (__fp16)a.y; h[2] = (__fp16)a.z; h[3] = (__fp16)a.w;
    h[4] = (__fp16)c.x; h[5] = (__fp16)c.y; h[6] = (__fp16)c.z; h[7] = (__fp16)c.w;
    *reinterpret_cast<h16x8*>(&w2s[p * 64 + ((ooc ^ (p & 7)) << 3)]) = h;
  }
  for (int idx = tid; idx < 576; idx += 256) w1l[idx] = cc1_w[idx];
  if (tid < 64) { b1l[tid] = cc1_b[tid]; b2l[tid] = cc2_b[tid]; }
  __syncthreads();

  // ---- phase 1: grouped 3x3 + GELU -> gs (f16, swizzled) ----
  {
    const int ty = tid >> 5, tx = tid & 31;
    const int rl = tx >> 4;            // local output row 0/1
    const int cb = (tx & 15) * 8;      // local col base
    float m[3][10];
#pragma unroll
    for (int dr = 0; dr < 3; ++dr)
#pragma unroll
      for (int t = 0; t < 10; ++t)
        m[dr][t] = midl[(ty * 4 + rl + dr) * 132 + cb + t];
    const int pxb = rl * 128 + cb;
#pragma unroll
    for (int hh = 0; hh < 2; ++hh) {
      float g[8][4];
#pragma unroll
      for (int j = 0; j < 8; ++j) {
        const int oo = ty * 8 + j;
        float w[9];
#pragma unroll
        for (int t = 0; t < 9; ++t) w[t] = w1l[oo * 9 + t];
        const float bb = b1l[oo];
#pragma unroll
        for (int i2 = 0; i2 < 4; ++i2) {
          const int i = hh * 4 + i2;
          float a = bb;
#pragma unroll
          for (int dr = 0; dr < 3; ++dr)
#pragma unroll
            for (int dc = 0; dc < 3; ++dc)
              a += w[dr * 3 + dc] * m[dr][i + dc];
          g[j][i2] = 0.5f * a * (1.f + erff(a * 0.70710678118654752f));
        }
      }
#pragma unroll
      for (int i2 = 0; i2 < 4; ++i2) {
        const int px = pxb + hh * 4 + i2;
        const int swz = (px ^ (px >> 3)) & 7;
        h16x8 h;
#pragma unroll
        for (int j = 0; j < 8; ++j) h[j] = (__fp16)g[j][i2];
        *reinterpret_cast<h16x8*>(&gs[px * 64 + ((ty ^ swz) << 3)]) = h;
      }
    }
  }
  __syncthreads();

  // ---- phase 2: out[p][px] = b2[p] + sum_oo w2[p][oo]*g[oo][px] via MFMA ----
  const int wv = tid >> 6, lane = tid & 63;
  const int n0 = wv * 64;
  const int lr = lane & 15, lg = lane >> 4;
  f32x4 acc[4][4];
#pragma unroll
  for (int mt = 0; mt < 4; ++mt)
#pragma unroll
    for (int nt = 0; nt < 4; ++nt) acc[mt][nt] = (f32x4){0.f, 0.f, 0.f, 0.f};
#pragma unroll
  for (int ks = 0; ks < 2; ++ks) {
    const int ooc = ks * 4 + lg;
    h16x8 af[4], bfr[4];
#pragma unroll
    for (int mt = 0; mt < 4; ++mt) {
      const int p = mt * 16 + lr;
      af[mt] = *reinterpret_cast<const h16x8*>(
          &w2s[p * 64 + ((ooc ^ (p & 7)) << 3)]);
    }
#pragma unroll
    for (int nt = 0; nt < 4; ++nt) {
      const int px = n0 + nt * 16 + lr;
      const int swz = (px ^ (px >> 3)) & 7;
      bfr[nt] = *reinterpret_cast<const h16x8*>(
          &gs[px * 64 + ((ooc ^ swz) << 3)]);
    }
#pragma unroll
    for (int mt = 0; mt < 4; ++mt)
#pragma unroll
      for (int nt = 0; nt < 4; ++nt)
        acc[mt][nt] = __builtin_amdgcn_mfma_f32_16x16x32_f16(
            af[mt], bfr[nt], acc[mt][nt], 0, 0, 0);
  }
  // ---- epilogue: C col = px (lane&15), row = p ((lane>>4)*4+r) ----
#pragma unroll
  for (int mt = 0; mt < 4; ++mt) {
#pragma unroll
    for (int r = 0; r < 4; ++r) {
      const int p = mt * 16 + lg * 4 + r;
      const float bv = b2l[p];
      float* op = out + (size_t)(b * 64 + p) * HW_;
#pragma unroll
      for (int nt = 0; nt < 4; ++nt) {
        const int px = n0 + nt * 16 + lr;
        const int grow = r0 + (px >> 7), gcol = c0 + (px & 127);
        op[(size_t)grow * W_ + gcol] = acc[mt][nt][r] + bv;
      }
    }
  }
}

// ---------------------------------------------------------------------------
extern "C" void kernel_launch(void* const* d_in, const int* in_sizes, int n_in,
                              void* d_out, int out_size, void* d_ws, size_t ws_size,
                              hipStream_t stream) {
  const float* x        = (const float*)d_in[0];
  const float* metainfo = (const float*)d_in[1];
  const float* Wq       = (const float*)d_in[2];
  const float* bq       = (const float*)d_in[3];
  const float* temps    = (const float*)d_in[4];
  const float* kv_w     = (const float*)d_in[5];
  const float* kv_b     = (const float*)d_in[6];
  const float* dw_w     = (const float*)d_in[7];
  const float* dw_b     = (const float*)d_in[8];
  const float* cc1_w    = (const float*)d_in[9];
  const float* cc1_b    = (const float*)d_in[10];
  const float* cc2_w    = (const float*)d_in[11];
  const float* cc2_b    = (const float*)d_in[12];
  float* out = (float*)d_out;

  // ws layout (float offsets): kv1 bf16 occupies [0, 33554432) float-equiv.
  float* ws      = (float*)d_ws;
  bf16*  kv1     = (bf16*)d_ws;           // 2*128*HW bf16 = 134.2 MB
  float* mid     = ws + 33554432;         // 2*8*HW fp32   = 16.8 MB
  float* small_  = ws + 37748736;
  float* ssqpart = small_;                // 2*64*16 = 2048
  float* rnorm   = small_ + 2560;         // 128
  float* qn      = small_ + 2688;         // 512
  float* dpart   = small_ + 3200;         // 64*64 = 4096

  // k (bf16) and v (bf16) live in d_out until K5 overwrites it with fp32 out.
  bf16* kvout = (bf16*)d_out;             // [k: 2*64*HW][v: 2*64*HW] bf16

  k1a_conv1x1<<<1024, 256, 0, stream>>>(x, kv_w, kv_b, kv1);
  k1b_dw<<<dim3(16, 32, 2), 256, 0, stream>>>(kv1, dw_w, dw_b, kvout, ssqpart);
  k2_finalize<<<1, 256, 0, stream>>>(ssqpart, temps, metainfo, Wq, bq,
                                     rnorm, qn);
  k3_denom<<<dim3(64, 8, 2), 256, 0, stream>>>(kvout, qn, dpart);
  k4_attend<<<dim3(256, 2), 256, 0, stream>>>(kvout, qn, dpart, mid);
  k5_cross<<<dim3(4, 256, 2), 256, 0, stream>>>(mid, cc1_w, cc1_b, cc2_w,
                                                cc2_b, out);
}

// Round 13
// 266.175 us; speedup vs baseline: 1.0399x; 1.0399x over previous
//
#include <hip/hip_runtime.h>
#include <hip/hip_bf16.h>

#define B_    2
#define H_    512
#define W_    512
#define HW_   262144   // 512*512
#define EPSV  1e-12f

typedef __hip_bfloat16 bf16;
typedef __fp16 h16x8 __attribute__((ext_vector_type(8)));
typedef float f32x4 __attribute__((ext_vector_type(4)));

// ---------------------------------------------------------------------------
// K1a: 1x1 conv as f16 MFMA GEMM, 4 tiles/block, software-pipelined, with
// single-pass LDS-bounce epilogue (R11 version: 83 us measured).
__global__ __launch_bounds__(256) void k1a_conv1x1(
    const float* __restrict__ x, const float* __restrict__ kv_w,
    const float* __restrict__ kv_b, bf16* __restrict__ kv1) {
  const int tid = threadIdx.x;
  const int base = blockIdx.x * 512;   // 4 tiles of 128 px, same b
  const int b  = base >> 18;
  const int sb = base & (HW_ - 1);
  __shared__ __fp16 Wl[8 * 128 * 8];   // [kg][o][e]    16 KB
  __shared__ __fp16 Xe[8 * 64 * 8];    // [kg][px/2][e]  8 KB (even px)
  __shared__ __fp16 Xo[8 * 64 * 8];    // [kg][px/2][e]  8 KB (odd px)
  __shared__ bf16 Bo[128 * 136];       // bounce [o][px], stride 136 = 34 KB

  // ---- stage W once: thread t -> o = t>>1, k-half = t&1 (32 k's) ----
  {
    const int o = tid >> 1, half = tid & 1;
    const float* wp = kv_w + o * 64 + half * 32;
#pragma unroll
    for (int j = 0; j < 4; ++j) {
      const float4 a = *reinterpret_cast<const float4*>(wp + j * 8);
      const float4 c = *reinterpret_cast<const float4*>(wp + j * 8 + 4);
      h16x8 h;
      h[0] = (__fp16)a.x; h[1] = (__fp16)a.y; h[2] = (__fp16)a.z; h[3] = (__fp16)a.w;
      h[4] = (__fp16)c.x; h[5] = (__fp16)c.y; h[6] = (__fp16)c.z; h[7] = (__fp16)c.w;
      *reinterpret_cast<h16x8*>(&Wl[((half * 4 + j) * 128 + o) * 8]) = h;
    }
  }
  // ---- x staging geometry: thread -> px pair (2m,2m+1), 16 planes ----
  const int m = tid & 63, kgq = tid >> 6;
  const float* xbase = x + (size_t)b * 64 * HW_ + sb + m * 2;

  float2 cur[16], nxt[16];
#pragma unroll
  for (int u = 0; u < 16; ++u)
    cur[u] = *reinterpret_cast<const float2*>(xbase + (size_t)(kgq * 16 + u) * HW_);

  const int wv = tid >> 6, lane = tid & 63;
  const int m0 = (wv & 1) * 64, n0 = (wv >> 1) * 64;
  const int lr = lane & 15, lg = lane >> 4;

#pragma unroll
  for (int t = 0; t < 4; ++t) {
    // ---- pack cur -> LDS (single buffer; WAR-safe via bounce barrier) ----
#pragma unroll
    for (int kk = 0; kk < 2; ++kk) {
      h16x8 he, ho;
#pragma unroll
      for (int e = 0; e < 8; ++e) {
        he[e] = (__fp16)cur[kk * 8 + e].x;
        ho[e] = (__fp16)cur[kk * 8 + e].y;
      }
      const int kg = kgq * 2 + kk;
      *reinterpret_cast<h16x8*>(&Xe[(kg * 64 + m) * 8]) = he;
      *reinterpret_cast<h16x8*>(&Xo[(kg * 64 + m) * 8]) = ho;
    }
    __syncthreads();   // barA: pack visible
    // ---- prefetch next tile's x (issues overlap MFMA + epilogue) ----
    if (t < 3) {
#pragma unroll
      for (int u = 0; u < 16; ++u)
        nxt[u] = *reinterpret_cast<const float2*>(
            xbase + (t + 1) * 128 + (size_t)(kgq * 16 + u) * HW_);
    }
    // ---- MFMA: wave covers M-half (wv&1)*64, N-half (wv>>1)*64 ----
    const __fp16* xb2 = (lr & 1) ? Xo : Xe;
    f32x4 acc[4][4];
#pragma unroll
    for (int mt = 0; mt < 4; ++mt)
#pragma unroll
      for (int nt = 0; nt < 4; ++nt) acc[mt][nt] = (f32x4){0.f, 0.f, 0.f, 0.f};
#pragma unroll
    for (int ks = 0; ks < 2; ++ks) {
      h16x8 af[4], bfr[4];
#pragma unroll
      for (int mt = 0; mt < 4; ++mt)
        af[mt] = *reinterpret_cast<const h16x8*>(
            &Wl[((ks * 4 + lg) * 128 + m0 + mt * 16 + lr) * 8]);
#pragma unroll
      for (int nt = 0; nt < 4; ++nt)
        bfr[nt] = *reinterpret_cast<const h16x8*>(
            &xb2[((ks * 4 + lg) * 64 + (n0 >> 1) + nt * 8 + (lr >> 1)) * 8]);
#pragma unroll
      for (int mt = 0; mt < 4; ++mt)
#pragma unroll
        for (int nt = 0; nt < 4; ++nt)
          acc[mt][nt] = __builtin_amdgcn_mfma_f32_16x16x32_f16(
              af[mt], bfr[nt], acc[mt][nt], 0, 0, 0);
    }
    // ---- bounce acc (+bias, same rounding as before) into LDS ----
#pragma unroll
    for (int mt = 0; mt < 4; ++mt) {
#pragma unroll
      for (int r = 0; r < 4; ++r) {
        const int o = m0 + mt * 16 + lg * 4 + r;
        const float bv = kv_b[o];
#pragma unroll
        for (int nt = 0; nt < 4; ++nt)
          Bo[o * 136 + n0 + nt * 16 + lr] =
              __float2bfloat16(acc[mt][nt][r] + bv);
      }
    }
    __syncthreads();   // barB: bounce visible; also protects X for next pack
    // ---- coalesced stores: 4 full 256B o-rows per instruction ----
    {
      const int oo = tid >> 4;          // 0..15
      const int pxc = (tid & 15) * 8;   // 0..120
      bf16* dst = kv1 + (size_t)b * 128 * HW_ + sb + t * 128 + pxc;
#pragma unroll
      for (int rr = 0; rr < 8; ++rr) {
        const int o = oo + rr * 16;
        const int4 v = *reinterpret_cast<const int4*>(&Bo[o * 136 + pxc]);
        *reinterpret_cast<int4*>(dst + (size_t)o * HW_) = v;
      }
    }
    // ---- rotate prefetch registers ----
    if (t < 3) {
#pragma unroll
      for (int u = 0; u < 16; ++u) cur[u] = nxt[u];
    }
  }
}

// ---------------------------------------------------------------------------
// K1b: depthwise 3x3 (pad=1) on bf16 kv1 -> bf16 k||v (in d_out), fp32 math.
// Halo cols via wave shuffle.
__global__ __launch_bounds__(256) void k1b_dw(
    const bf16* __restrict__ kv1, const float* __restrict__ dw_w,
    const float* __restrict__ dw_b, bf16* __restrict__ kvout,
    float* __restrict__ ssqpart) {
  const int tid = threadIdx.x;
  const int cchunk = tid & 63;            // 64 col-chunks of 8
  const int ch_sub = tid >> 6;            // 4 channels per block
  const int rs = blockIdx.x;              // 16 row strips of 32
  const int chgrp = blockIdx.y;           // 32
  const int b = blockIdx.z;
  const int ch = chgrp * 4 + ch_sub;
  const int c0 = cchunk * 8;
  const int r0 = rs * 32;
  const bf16* src = kv1 + (size_t)(b * 128 + ch) * HW_;
  const bool is_k = (ch < 64);
  const size_t obase = is_k ? (size_t)(b * 64 + ch) * HW_
                            : (size_t)(128 + b * 64 + (ch - 64)) * HW_;
  bf16* dst = kvout + obase;
  float dwr[9];
#pragma unroll
  for (int t = 0; t < 9; ++t) dwr[t] = dw_w[ch * 9 + t];
  const float bd = dw_b[ch];

  float a0[10], a1[10], a2[10];
  auto loadrow = [&](int gr, float* a) {
    if (gr < 0 || gr >= H_) {
#pragma unroll
      for (int t = 0; t < 10; ++t) a[t] = 0.f;
      return;
    }
    union { int4 v; bf16 h[8]; } raw;
    raw.v = *reinterpret_cast<const int4*>(src + (size_t)gr * W_ + c0);
#pragma unroll
    for (int t = 0; t < 8; ++t) a[t + 1] = __bfloat162float(raw.h[t]);
    const float left = __shfl_up(a[8], 1);     // lane-1's col c0-1
    const float right = __shfl_down(a[1], 1);  // lane+1's col c0+8
    a[0] = (cchunk == 0) ? 0.f : left;
    a[9] = (cchunk == 63) ? 0.f : right;
  };
  loadrow(r0 - 1, a0);
  loadrow(r0, a1);
  float sq = 0.f;
#pragma unroll 4
  for (int rr = 0; rr < 32; ++rr) {
    loadrow(r0 + rr + 1, a2);
    union { int4 v; bf16 h[8]; } ou;
#pragma unroll
    for (int j = 0; j < 8; ++j) {
      const float ov = bd
          + dwr[0] * a0[j] + dwr[1] * a0[j + 1] + dwr[2] * a0[j + 2]
          + dwr[3] * a1[j] + dwr[4] * a1[j + 1] + dwr[5] * a1[j + 2]
          + dwr[6] * a2[j] + dwr[7] * a2[j + 1] + dwr[8] * a2[j + 2];
      sq += ov * ov;
      ou.h[j] = __float2bfloat16(ov);
    }
    *reinterpret_cast<int4*>(dst + (size_t)(r0 + rr) * W_ + c0) = ou.v;
#pragma unroll
    for (int t = 0; t < 10; ++t) { a0[t] = a1[t]; a1[t] = a2[t]; }
  }
  // wave reduction of sq over the 64 col-chunk lanes (same ch per wave)
#pragma unroll
  for (int off = 32; off > 0; off >>= 1) sq += __shfl_down(sq, off, 64);
  if (is_k && cchunk == 0)
    ssqpart[(size_t)(b * 64 + ch) * 16 + rs] = sq;
}

// ---------------------------------------------------------------------------
// K2: reduce sumsq partials -> rnorm; qn = sign(q)*rnorm*temps (k0 folded in)
__global__ __launch_bounds__(256) void k2_finalize(
    const float* __restrict__ ssqpart, const float* __restrict__ temps,
    const float* __restrict__ metainfo, const float* __restrict__ Wq,
    const float* __restrict__ bq, float* __restrict__ rnorm,
    float* __restrict__ qn) {
  const int tid = threadIdx.x;
  if (tid < 128) {
    const int b = tid >> 6, c = tid & 63;
    float s = 0.f;
    for (int p = 0; p < 16; ++p) s += ssqpart[(size_t)(b * 64 + c) * 16 + p];
    rnorm[tid] = 1.f / fmaxf(sqrtf(s), EPSV);
  }
  __syncthreads();
  for (int idx = tid; idx < 512; idx += 256) {
    const int b = idx >> 8, n = (idx >> 6) & 3, d = idx & 63;
    float acc = bq[n * 64 + d];
#pragma unroll
    for (int m = 0; m < 4; ++m)
      acc += metainfo[(b * 4 + n) * 4 + m] * Wq[(n * 64 + d) * 4 + m];
    const float sgn = acc / fmaxf(fabsf(acc), EPSV);
    qn[idx] = sgn * rnorm[b * 64 + d] * temps[n * 8 + (d >> 3)];
  }
}

// ---------------------------------------------------------------------------
// K3: softmax denominators from bf16 k. 8 px/thread, 16B k loads.
__global__ __launch_bounds__(256) void k3_denom(
    const bf16* __restrict__ kbuf, const float* __restrict__ qn,
    float* __restrict__ dpart) {
  const int tile = blockIdx.x, e = blockIdx.y, b = blockIdx.z;
  const int tid = threadIdx.x;
  float q[4][8];
#pragma unroll
  for (int n = 0; n < 4; ++n)
#pragma unroll
    for (int cc = 0; cc < 8; ++cc)
      q[n][cc] = qn[b * 256 + n * 64 + e * 8 + cc];
  const bf16* kb = kbuf + (size_t)(b * 64 + e * 8) * HW_;
  float dsum[4] = {0.f, 0.f, 0.f, 0.f};
  const int sbase = tile * 4096;
#pragma unroll
  for (int it = 0; it < 2; ++it) {
    const int s = sbase + (it * 256 + tid) * 8;
    float kf[8][8];
#pragma unroll
    for (int cc = 0; cc < 8; ++cc) {
      union { int4 v; bf16 h[8]; } r;
      r.v = *reinterpret_cast<const int4*>(kb + (size_t)cc * HW_ + s);
#pragma unroll
      for (int j = 0; j < 8; ++j) kf[cc][j] = __bfloat162float(r.h[j]);
    }
#pragma unroll
    for (int n = 0; n < 4; ++n) {
#pragma unroll
      for (int px = 0; px < 8; ++px) {
        float l = 0.f;
#pragma unroll
        for (int cc = 0; cc < 8; ++cc) l += q[n][cc] * kf[cc][px];
        dsum[n] += __expf(l);
      }
    }
  }
  __shared__ float red[256];
#pragma unroll
  for (int n = 0; n < 4; ++n) {
    red[tid] = dsum[n];
    __syncthreads();
    for (int st = 128; st > 0; st >>= 1) {
      if (tid < st) red[tid] += red[tid + st];
      __syncthreads();
    }
    if (tid == 0) dpart[(b * 32 + n * 8 + e) * 64 + tile] = red[0];
    __syncthreads();
  }
}

// ---------------------------------------------------------------------------
// K4: mid[b,cc,s] = sum_e (sum_n exp(l)/denom) * v[b,e,cc,s]  (bf16 k,v)
__global__ __launch_bounds__(256) void k4_attend(
    const bf16* __restrict__ kvbuf, const float* __restrict__ qn,
    const float* __restrict__ dpart, float* __restrict__ mid) {
  const int b = blockIdx.y;
  const int tid = threadIdx.x;
  __shared__ float qnl[256];
  __shared__ float rdl[32];
  qnl[tid] = qn[b * 256 + tid];
  if (tid < 32) {
    float s = 0.f;
    for (int t = 0; t < 64; ++t) s += dpart[(b * 32 + tid) * 64 + t];
    rdl[tid] = 1.f / s;
  }
  __syncthreads();
  const bf16* kb = kvbuf + (size_t)(b * 64) * HW_;
  const bf16* vb = kvbuf + (size_t)(128 + b * 64) * HW_;
  float* mb = mid + (size_t)b * 8 * HW_;
  const int s = (blockIdx.x * 256 + tid) * 4;
  float macc[8][4];
#pragma unroll
  for (int cc = 0; cc < 8; ++cc)
#pragma unroll
    for (int px = 0; px < 4; ++px) macc[cc][px] = 0.f;
#pragma unroll
  for (int e = 0; e < 8; ++e) {
    float kf[8][4];
#pragma unroll
    for (int cc = 0; cc < 8; ++cc) {
      union { ushort4 v; bf16 h[4]; } r;
      r.v = *reinterpret_cast<const ushort4*>(kb + (size_t)(e * 8 + cc) * HW_ + s);
#pragma unroll
      for (int px = 0; px < 4; ++px) kf[cc][px] = __bfloat162float(r.h[px]);
    }
    float wsum[4] = {0.f, 0.f, 0.f, 0.f};
#pragma unroll
    for (int n = 0; n < 4; ++n) {
      const float rd = rdl[n * 8 + e];
#pragma unroll
      for (int px = 0; px < 4; ++px) {
        float l = 0.f;
#pragma unroll
        for (int cc = 0; cc < 8; ++cc) l += qnl[n * 64 + e * 8 + cc] * kf[cc][px];
        wsum[px] += __expf(l) * rd;
      }
    }
#pragma unroll
    for (int cc = 0; cc < 8; ++cc) {
      union { ushort4 v; bf16 h[4]; } r;
      r.v = *reinterpret_cast<const ushort4*>(vb + (size_t)(e * 8 + cc) * HW_ + s);
#pragma unroll
      for (int px = 0; px < 4; ++px)
        macc[cc][px] += wsum[px] * __bfloat162float(r.h[px]);
    }
  }
#pragma unroll
  for (int cc = 0; cc < 8; ++cc)
    *reinterpret_cast<float4*>(mb + (size_t)cc * HW_ + s) =
        make_float4(macc[cc][0], macc[cc][1], macc[cc][2], macc[cc][3]);
}

// ---------------------------------------------------------------------------
// K5: grouped 3x3 (8->64, groups=8) + exact GELU + 1x1 (64->64) via f16 MFMA.
// NEW: LDS-bounce fp32 epilogue in 4 mt-passes (16 dwordx4 stores/thread
// instead of 64 scalar dword stores). Bounce buffer aliases the dead midl.
__global__ __launch_bounds__(256) void k5_cross(
    const float* __restrict__ mid, const float* __restrict__ cc1_w,
    const float* __restrict__ cc1_b, const float* __restrict__ cc2_w,
    const float* __restrict__ cc2_b, float* __restrict__ out) {
  const int tid = threadIdx.x;
  const int c0 = blockIdx.x * 128;
  const int r0 = blockIdx.y * 2;
  const int b = blockIdx.z;
  __shared__ union {
    float midl[8 * 4 * 132];   // [ch][4 rows][132] (phase 1)
    float bo[16 * 268];        // bounce [p16][px], stride 268 (epilogue)
  } shm;
  __shared__ __fp16 gs[256 * 64];       // [px][oo] swizzled  32 KB
  __shared__ __fp16 w2s[64 * 64];       // [p][oo] swizzled    8 KB
  __shared__ float w1l[576];
  __shared__ float b1l[64], b2l[64];
  // stage mid tile (coalesced along cols)
  for (int idx = tid; idx < 8 * 4 * 130; idx += 256) {
    const int ch = idx / 520;
    const int rem = idx % 520;
    const int dr = rem / 130, lc = rem % 130;
    const int gr = r0 - 1 + dr, gc = c0 - 1 + lc;
    float v = 0.f;
    if (gr >= 0 && gr < H_ && gc >= 0 && gc < W_)
      v = mid[(size_t)(b * 8 + ch) * HW_ + (size_t)gr * W_ + gc];
    shm.midl[(ch * 4 + dr) * 132 + lc] = v;
  }
  // stage w2 as f16 chunks: w2s[p][ooc^(p&7)] = cc2_w[p][ooc*8..+8]
#pragma unroll
  for (int rr = 0; rr < 2; ++rr) {
    const int idx = tid + rr * 256;
    const int p = idx >> 3, ooc = idx & 7;
    const float4 a = *reinterpret_cast<const float4*>(cc2_w + p * 64 + ooc * 8);
    const float4 c = *reinterpret_cast<const float4*>(cc2_w + p * 64 + ooc * 8 + 4);
    h16x8 h;
    h[0] = (__fp16)a.x; h[1] = (__fp16)a.y; h[2] = (__fp16)a.z; h[3] = (__fp16)a.w;
    h[4] = (__fp16)c.x; h[5] = (__fp16)c.y; h[6] = (__fp16)c.z; h[7] = (__fp16)c.w;
    *reinterpret_cast<h16x8*>(&w2s[p * 64 + ((ooc ^ (p & 7)) << 3)]) = h;
  }
  for (int idx = tid; idx < 576; idx += 256) w1l[idx] = cc1_w[idx];
  if (tid < 64) { b1l[tid] = cc1_b[tid]; b2l[tid] = cc2_b[tid]; }
  __syncthreads();

  // ---- phase 1: grouped 3x3 + GELU -> gs (f16, swizzled) ----
  {
    const int ty = tid >> 5, tx = tid & 31;
    const int rl = tx >> 4;            // local output row 0/1
    const int cb = (tx & 15) * 8;      // local col base
    float m[3][10];
#pragma unroll
    for (int dr = 0; dr < 3; ++dr)
#pragma unroll
      for (int t = 0; t < 10; ++t)
        m[dr][t] = shm.midl[(ty * 4 + rl + dr) * 132 + cb + t];
    const int pxb = rl * 128 + cb;
#pragma unroll
    for (int hh = 0; hh < 2; ++hh) {
      float g[8][4];
#pragma unroll
      for (int j = 0; j < 8; ++j) {
        const int oo = ty * 8 + j;
        float w[9];
#pragma unroll
        for (int t = 0; t < 9; ++t) w[t] = w1l[oo * 9 + t];
        const float bb = b1l[oo];
#pragma unroll
        for (int i2 = 0; i2 < 4; ++i2) {
          const int i = hh * 4 + i2;
          float a = bb;
#pragma unroll
          for (int dr = 0; dr < 3; ++dr)
#pragma unroll
            for (int dc = 0; dc < 3; ++dc)
              a += w[dr * 3 + dc] * m[dr][i + dc];
          g[j][i2] = 0.5f * a * (1.f + erff(a * 0.70710678118654752f));
        }
      }
#pragma unroll
      for (int i2 = 0; i2 < 4; ++i2) {
        const int px = pxb + hh * 4 + i2;
        const int swz = (px ^ (px >> 3)) & 7;
        h16x8 h;
#pragma unroll
        for (int j = 0; j < 8; ++j) h[j] = (__fp16)g[j][i2];
        *reinterpret_cast<h16x8*>(&gs[px * 64 + ((ty ^ swz) << 3)]) = h;
      }
    }
  }
  __syncthreads();

  // ---- phase 2: out[p][px] = b2[p] + sum_oo w2[p][oo]*g[oo][px] via MFMA ----
  const int wv = tid >> 6, lane = tid & 63;
  const int n0 = wv * 64;
  const int lr = lane & 15, lg = lane >> 4;
  f32x4 acc[4][4];
#pragma unroll
  for (int mt = 0; mt < 4; ++mt)
#pragma unroll
    for (int nt = 0; nt < 4; ++nt) acc[mt][nt] = (f32x4){0.f, 0.f, 0.f, 0.f};
#pragma unroll
  for (int ks = 0; ks < 2; ++ks) {
    const int ooc = ks * 4 + lg;
    h16x8 af[4], bfr[4];
#pragma unroll
    for (int mt = 0; mt < 4; ++mt) {
      const int p = mt * 16 + lr;
      af[mt] = *reinterpret_cast<const h16x8*>(
          &w2s[p * 64 + ((ooc ^ (p & 7)) << 3)]);
    }
#pragma unroll
    for (int nt = 0; nt < 4; ++nt) {
      const int px = n0 + nt * 16 + lr;
      const int swz = (px ^ (px >> 3)) & 7;
      bfr[nt] = *reinterpret_cast<const h16x8*>(
          &gs[px * 64 + ((ooc ^ swz) << 3)]);
    }
#pragma unroll
    for (int mt = 0; mt < 4; ++mt)
#pragma unroll
      for (int nt = 0; nt < 4; ++nt)
        acc[mt][nt] = __builtin_amdgcn_mfma_f32_16x16x32_f16(
            af[mt], bfr[nt], acc[mt][nt], 0, 0, 0);
  }
  // ---- epilogue via LDS bounce: 4 passes of 16 p-rows ----
  // C layout: col px = n0+nt*16+lr, row p = mt*16+lg*4+r (verified R7/R8).
  const int prow = tid >> 4;          // 0..15 (store row within pass)
  const int ci = (tid & 15) * 4;      // store col base 0..60
#pragma unroll
  for (int mt = 0; mt < 4; ++mt) {
    __syncthreads();   // previous pass's reads done before overwrite
#pragma unroll
    for (int r = 0; r < 4; ++r) {
      const int pl = lg * 4 + r;      // 0..15
      const float bv = b2l[mt * 16 + pl];
#pragma unroll
      for (int nt = 0; nt < 4; ++nt)
        shm.bo[pl * 268 + n0 + nt * 16 + lr] = acc[mt][nt][r] + bv;
    }
    __syncthreads();   // bounce visible
    const int p = mt * 16 + prow;
    float* op = out + (size_t)(b * 64 + p) * HW_;
#pragma unroll
    for (int j = 0; j < 4; ++j) {
      const int px = j * 64 + ci;
      const int grow = r0 + (px >> 7), gcol = c0 + (px & 127);
      const float4 v = *reinterpret_cast<const float4*>(&shm.bo[prow * 268 + px]);
      *reinterpret_cast<float4*>(op + (size_t)grow * W_ + gcol) = v;
    }
  }
}

// ---------------------------------------------------------------------------
extern "C" void kernel_launch(void* const* d_in, const int* in_sizes, int n_in,
                              void* d_out, int out_size, void* d_ws, size_t ws_size,
                              hipStream_t stream) {
  const float* x        = (const float*)d_in[0];
  const float* metainfo = (const float*)d_in[1];
  const float* Wq       = (const float*)d_in[2];
  const float* bq       = (const float*)d_in[3];
  const float* temps    = (const float*)d_in[4];
  const float* kv_w     = (const float*)d_in[5];
  const float* kv_b     = (const float*)d_in[6];
  const float* dw_w     = (const float*)d_in[7];
  const float* dw_b     = (const float*)d_in[8];
  const float* cc1_w    = (const float*)d_in[9];
  const float* cc1_b    = (const float*)d_in[10];
  const float* cc2_w    = (const float*)d_in[11];
  const float* cc2_b    = (const float*)d_in[12];
  float* out = (float*)d_out;

  // ws layout (float offsets): kv1 bf16 occupies [0, 33554432) float-equiv.
  float* ws      = (float*)d_ws;
  bf16*  kv1     = (bf16*)d_ws;           // 2*128*HW bf16 = 134.2 MB
  float* mid     = ws + 33554432;         // 2*8*HW fp32   = 16.8 MB
  float* small_  = ws + 37748736;
  float* ssqpart = small_;                // 2*64*16 = 2048
  float* rnorm   = small_ + 2560;         // 128
  float* qn      = small_ + 2688;         // 512
  float* dpart   = small_ + 3200;         // 64*64 = 4096

  // k (bf16) and v (bf16) live in d_out until K5 overwrites it with fp32 out.
  bf16* kvout = (bf16*)d_out;             // [k: 2*64*HW][v: 2*64*HW] bf16

  k1a_conv1x1<<<1024, 256, 0, stream>>>(x, kv_w, kv_b, kv1);
  k1b_dw<<<dim3(16, 32, 2), 256, 0, stream>>>(kv1, dw_w, dw_b, kvout, ssqpart);
  k2_finalize<<<1, 256, 0, stream>>>(ssqpart, temps, metainfo, Wq, bq,
                                     rnorm, qn);
  k3_denom<<<dim3(64, 8, 2), 256, 0, stream>>>(kvout, qn, dpart);
  k4_attend<<<dim3(256, 2), 256, 0, stream>>>(kvout, qn, dpart, mid);
  k5_cross<<<dim3(4, 256, 2), 256, 0, stream>>>(mid, cc1_w, cc1_b, cc2_w,
                                                cc2_b, out);
}